// Round 5
// baseline (237.160 us; speedup 1.0000x reference)
//
#include <hip/hip_runtime.h>

// ROI Align (FPN, PH=PW=7, SR=2), fp32 I/O.
// R14 = hybrid: LDS-staged path for levels 1-3 + R12 global-gather path for
// level 0.
// Post-mortem R9-R13: four kernels with FETCH 4x-varying, lane-slots
// 1.75x-varying, occupancy 3x-varying all land 69-74us. Every quantitative
// reduction of the divergent-gather stream failed => the cost is per
// divergent INSTRUCTION x lines-touched (TA/TD line serialization), not
// per byte / per lane-slot. Fix = change access TYPE: coalesced patch
// staging into LDS + LDS gathers.
//  - levels 1-3 (75% of rois): patch/channel <= 3.8KB. Block=(roi, 64ch),
//    stage C channels/chunk into 32KB LDS with coalesced 4B loads
//    (~300 wave-instr/block, exact-range => no clamping needed), then each
//    thread = (channel-row, px) gathers 8 LDS floats per output.
//  - level 0: patches large, gather redundancy low => keep R12 global path
//    (hardcoded l0; wide-roi branch retained).
// Predicted: dur 73.8 -> 40-50us if theory right; FETCH -> 90-110MB;
// WRITE 25.1 unchanged; LDS_BANK_CONFLICT nonzero.
// Rule: flat => vector-memory is not the wall; pivot to SQ/CP investigation.

#define NUM_CH    256
#define WPR       49          // waves per roi in the l0 global path
#define LDS_BYTES 32768

typedef float floatx2 __attribute__((ext_vector_type(2)));
typedef float floatx4 __attribute__((ext_vector_type(4)));

__device__ __forceinline__ float ext4(floatx4 v, int i) {
    float r = (i == 1) ? v.y : v.x;
    r = (i == 2) ? v.z : r;
    r = (i == 3) ? v.w : r;
    return r;
}

__global__ __launch_bounds__(256) void roi_align_kernel(
    const float* __restrict__ f0,
    const float* __restrict__ f1,
    const float* __restrict__ f2,
    const float* __restrict__ f3,
    const float* __restrict__ rois_f,
    const int* __restrict__ level,
    float* __restrict__ out,
    int K,                           // number of rois
    int GBLK)                        // blocks in the level-0 global region
{
    extern __shared__ float smem[];

    if ((int)blockIdx.x >= GBLK) {
        // ================= staged path: levels 1..3 =======================
        int b = blockIdx.x - GBLK;
        int k = b >> 2;              // roi (uniform across the whole block)
        int q = b & 3;               // channel quarter (64 channels)
        int lvl = level[k];
        if (lvl == 0) return;        // whole block exits together (k uniform)

        const float* f; int H, W; float scale;
        if (lvl == 1)      { f = f1; H = 100; W = 100; scale = 0.125f;   }
        else if (lvl == 2) { f = f2; H = 50;  W = 50;  scale = 0.0625f;  }
        else               { f = f3; H = 25;  W = 25;  scale = 0.03125f; }

        const float* rf = rois_f + (size_t)k * 5;
        float r0 = rf[0];
        float x1 = rf[1] * scale, y1 = rf[2] * scale;
        float x2 = rf[3] * scale, y2 = rf[4] * scale;
        int bi = (int)r0;
        bi = (bi < 0) ? 0 : ((bi > 1) ? 1 : bi);

        float bh = fmaxf(y2 - y1, 1.0f) * (1.0f / 7.0f);
        float bw = fmaxf(x2 - x1, 1.0f) * (1.0f / 7.0f);

        // ---- exact patch bounds (all sample corners lie inside; rois are
        //      in-image so sample coords are in [0,W) -> no clamping on
        //      staged addresses) -----------------------------------------
        float syn = y1 + 0.25f * bh, syx = y1 + 6.75f * bh;
        int y0  = min((int)fmaxf(syn, 0.0f), H - 1);
        int ylx = min((int)fmaxf(syx, 0.0f), H - 1);
        int yhx = min(ylx + 1, H - 1);
        int R   = yhx - y0 + 1;
        float sxn = x1 + 0.25f * bw, sxx = x1 + 6.75f * bw;
        int x0  = min((int)fmaxf(sxn, 0.0f), W - 1);
        int xlx = min((int)fmaxf(sxx, 0.0f), W - 1);
        int xhx = min(xlx + 1, W - 1);
        int XC  = xhx - x0 + 1;

        int patch = R * XC;                           // floats per channel
        int C = (LDS_BYTES / 4) / patch;              // channels per chunk
        C = min(C, 64); C = max(C, 1);

        // ---- per-thread geometry: thread = (cR, px), px fixed ------------
        int tid = threadIdx.x;
        int px  = tid % 49;
        int cR  = tid / 49;          // 0..4 compute rows; 5 = staging-only
        int ph = px / 7, pw = px % 7;

        int ra[2], rb[2]; float lyv[2], hyv[2], vyv[2];
        #pragma unroll
        for (int sy = 0; sy < 2; ++sy) {
            float y = y1 + (float)ph * bh + ((float)sy + 0.5f) * (bh * 0.5f);
            bool valid = (y > -1.0f) && (y < (float)H);
            float yc = fmaxf(y, 0.0f);
            int yl = min((int)yc, H - 1);
            int yh = min(yl + 1, H - 1);
            float ly = (yl >= H - 1) ? 0.0f : (yc - (float)yl);
            ra[sy] = (yl - y0) * XC;
            rb[sy] = (yh - y0) * XC;
            lyv[sy] = ly; hyv[sy] = 1.0f - ly;
            vyv[sy] = valid ? 0.25f : 0.0f;   // fold 2x2 mean into validity
        }
        int xa[2], xb[2]; float lxv[2], hxv[2], vxv[2];
        #pragma unroll
        for (int sx = 0; sx < 2; ++sx) {
            float x = x1 + (float)pw * bw + ((float)sx + 0.5f) * (bw * 0.5f);
            bool valid = (x > -1.0f) && (x < (float)W);
            float xc = fmaxf(x, 0.0f);
            int xl = min((int)xc, W - 1);
            float lx = (xl >= W - 1) ? 0.0f : (xc - (float)xl);
            xa[sx] = xl - x0;
            xb[sx] = min(xl + 1, W - 1) - x0;
            lxv[sx] = lx; hxv[sx] = 1.0f - lx;
            vxv[sx] = valid ? 1.0f : 0.0f;
        }

        const size_t plane = (size_t)(H * W);
        const float* basec = f + ((size_t)bi * NUM_CH + q * 64) * plane;
        size_t outb = (size_t)k * (NUM_CH * 49) + (size_t)(q * 64) * 49 + px;

        // ---- chunk loop: stage C channels, compute, repeat ---------------
        for (int c0 = 0; c0 < 64; c0 += C) {
            int Cc = min(C, 64 - c0);
            int slots = Cc * patch;
            // coalesced staging: s -> (c, r, x); consecutive tid -> x-major
            for (int s = tid; s < slots; s += 256) {
                int c   = s / patch;
                int rem = s - c * patch;
                int r   = rem / XC;
                int x   = rem - r * XC;
                smem[s] = basec[(size_t)(c0 + c) * plane
                                + (size_t)((y0 + r) * W + x0 + x)];
            }
            __syncthreads();
            if (cR < 5) {
                for (int cc = cR; cc < Cc; cc += 5) {
                    const float* P = smem + cc * patch;
                    float acc = 0.0f;
                    #pragma unroll
                    for (int sy = 0; sy < 2; ++sy) {
                        #pragma unroll
                        for (int sx = 0; sx < 2; ++sx) {
                            float v00 = P[ra[sy] + xa[sx]];
                            float v01 = P[ra[sy] + xb[sx]];
                            float v10 = P[rb[sy] + xa[sx]];
                            float v11 = P[rb[sy] + xb[sx]];
                            float vs  = vyv[sy] * vxv[sx];
                            acc += vs * (hyv[sy] * (hxv[sx] * v00 + lxv[sx] * v01)
                                       + lyv[sy] * (hxv[sx] * v10 + lxv[sx] * v11));
                        }
                    }
                    out[outb + (size_t)(c0 + cc) * 49] = acc;
                }
            }
            __syncthreads();
        }
        return;
    }

    // ================= global-gather path: level 0 only ===================
    // R12 structure, hardcoded level 0 (f0, 200x200, scale 0.25).
    {
        int nb  = GBLK;
        int q   = nb >> 3, r = nb & 7;
        int xcd = blockIdx.x & 7;
        int idx = blockIdx.x >> 3;
        int l   = xcd * q + min(xcd, r) + idx;      // chunked XCD swizzle

        int NW  = K * WPR;
        int wid = l * 4 + (int)(threadIdx.x >> 6);
        if (wid >= NW) return;
        int lane = threadIdx.x & 63;

        int k = wid % K;                            // roi        (inner)
        int g = wid / K;                            // pair-group (outer)
        k = __builtin_amdgcn_readfirstlane(k);
        g = __builtin_amdgcn_readfirstlane(g);

        if (level[k] != 0) return;                  // staged path owns it

        const int H = 200, W = 200;
        const float scale = 0.25f;
        const float* f = f0;

        int pair = g * 64 + lane;                   // 0..3135
        int c2   = pair / 49;                       // channel group (x4 ch)
        int p    = pair - c2 * 49;
        int ph = p / 7;
        int pw = p % 7;

        const float* rf = rois_f + (size_t)k * 5;
        float r0 = rf[0];
        float x1 = rf[1] * scale, y1 = rf[2] * scale;
        float x2 = rf[3] * scale, y2 = rf[4] * scale;
        int bi = (int)r0;
        bi = (bi < 0) ? 0 : ((bi > 1) ? 1 : bi);

        float bh = fmaxf(y2 - y1, 1.0f) * (1.0f / 7.0f);
        float bw = fmaxf(x2 - x1, 1.0f) * (1.0f / 7.0f);

        const size_t plane = (size_t)(H * W);
        const float* base  = f + ((size_t)bi * NUM_CH + c2) * plane;
        const size_t cstr  = (size_t)64 * plane;    // stride between channels

        int   rA[2], rB[2];
        float lyv[2], hyv[2], vy[2];
        #pragma unroll
        for (int sy = 0; sy < 2; ++sy) {
            float y = y1 + (float)ph * bh + ((float)sy + 0.5f) * (bh * 0.5f);
            bool valid = (y > -1.0f) && (y < (float)H);
            float yc = fmaxf(y, 0.0f);
            int yl = min((int)yc, H - 1);
            int yh = min(yl + 1, H - 1);
            float ly = (yl >= H - 1) ? 0.0f : (yc - (float)yl);
            rA[sy] = yl * W;
            rB[sy] = yh * W;
            lyv[sy] = ly; hyv[sy] = 1.0f - ly;
            vy[sy] = valid ? 0.25f : 0.0f;
        }
        int   xlv[2], xhv[2];
        float lxv[2], hxv[2], vx[2];
        #pragma unroll
        for (int sx = 0; sx < 2; ++sx) {
            float x = x1 + (float)pw * bw + ((float)sx + 0.5f) * (bw * 0.5f);
            bool valid = (x > -1.0f) && (x < (float)W);
            float xc = fmaxf(x, 0.0f);
            int xl = min((int)xc, W - 1);
            float lx = (xl >= W - 1) ? 0.0f : (xc - (float)xl);
            xlv[sx] = xl;
            xhv[sx] = min(xl + 1, W - 1);
            lxv[sx] = lx; hxv[sx] = 1.0f - lx;
            vx[sx] = valid ? 1.0f : 0.0f;
        }

        bool same = (rA[1] == rA[0]);

        float acc[4];
        #pragma unroll
        for (int j = 0; j < 4; ++j) acc[j] = 0.0f;

        if (bw <= 3.98f) {
            int xq = min(xlv[0], W - 4);
            int i0l = min(max(xlv[0] - xq, 0), 3);
            int i0h = min(max(xhv[0] - xq, 0), 3);
            int i1l = min(max(xlv[1] - xq, 0), 3);
            int i1h = min(max(xhv[1] - xq, 0), 3);

            floatx4 LA[4], LB[4];
            #pragma unroll
            for (int j = 0; j < 4; ++j) {
                const float* bj = base + (size_t)j * cstr;
                LA[j] = *(const floatx4*)(bj + rA[0] + xq);
                LB[j] = *(const floatx4*)(bj + rB[0] + xq);
            }
            #pragma unroll
            for (int sy = 0; sy < 2; ++sy) {
                if (sy == 1 && !same) {
                    #pragma unroll
                    for (int j = 0; j < 4; ++j) {
                        const float* bj = base + (size_t)j * cstr;
                        LA[j] = *(const floatx4*)(bj + rA[1] + xq);
                        LB[j] = *(const floatx4*)(bj + rB[1] + xq);
                    }
                }
                #pragma unroll
                for (int sx = 0; sx < 2; ++sx) {
                    int il = sx ? i1l : i0l;
                    int ih = sx ? i1h : i0h;
                    float vs  = vy[sy] * vx[sx];
                    float w00 = hyv[sy] * hxv[sx] * vs;
                    float w01 = hyv[sy] * lxv[sx] * vs;
                    float w10 = lyv[sy] * hxv[sx] * vs;
                    float w11 = lyv[sy] * lxv[sx] * vs;
                    #pragma unroll
                    for (int j = 0; j < 4; ++j) {
                        acc[j] += w00 * ext4(LA[j], il) + w01 * ext4(LA[j], ih)
                                + w10 * ext4(LB[j], il) + w11 * ext4(LB[j], ih);
                    }
                }
            }
        } else {
            int   xbq[2];
            float sel[2];
            #pragma unroll
            for (int sx = 0; sx < 2; ++sx) {
                int xq = min(xlv[sx], W - 2);
                xbq[sx] = xq;
                sel[sx] = (xlv[sx] > xq) ? 1.0f : 0.0f;
            }
            floatx2 va[4][2], vb[4][2];
            #pragma unroll
            for (int sx = 0; sx < 2; ++sx) {
                #pragma unroll
                for (int j = 0; j < 4; ++j) {
                    const float* bj = base + (size_t)j * cstr;
                    va[j][sx] = *(const floatx2*)(bj + rA[0] + xbq[sx]);
                    vb[j][sx] = *(const floatx2*)(bj + rB[0] + xbq[sx]);
                }
            }
            #pragma unroll
            for (int sy = 0; sy < 2; ++sy) {
                if (sy == 1 && !same) {
                    #pragma unroll
                    for (int sx = 0; sx < 2; ++sx) {
                        #pragma unroll
                        for (int j = 0; j < 4; ++j) {
                            const float* bj = base + (size_t)j * cstr;
                            va[j][sx] = *(const floatx2*)(bj + rA[1] + xbq[sx]);
                            vb[j][sx] = *(const floatx2*)(bj + rB[1] + xbq[sx]);
                        }
                    }
                }
                #pragma unroll
                for (int sx = 0; sx < 2; ++sx) {
                    float vs  = vy[sy] * vx[sx];
                    float w00 = hyv[sy] * hxv[sx] * vs;
                    float w01 = hyv[sy] * lxv[sx] * vs;
                    float w10 = lyv[sy] * hxv[sx] * vs;
                    float w11 = lyv[sy] * lxv[sx] * vs;
                    float s0  = sel[sx];
                    #pragma unroll
                    for (int j = 0; j < 4; ++j) {
                        float v00 = va[j][sx].x + s0 * (va[j][sx].y - va[j][sx].x);
                        float v10 = vb[j][sx].x + s0 * (vb[j][sx].y - vb[j][sx].x);
                        acc[j] += w00 * v00 + w01 * va[j][sx].y
                                + w10 * v10 + w11 * vb[j][sx].y;
                    }
                }
            }
        }

        size_t ob = (size_t)k * (NUM_CH * 49) + (size_t)g * 64 + lane;
        #pragma unroll
        for (int j = 0; j < 4; ++j)
            out[ob + (size_t)j * 3136] = acc[j];
    }
}

extern "C" void kernel_launch(void* const* d_in, const int* in_sizes, int n_in,
                              void* d_out, int out_size, void* d_ws, size_t ws_size,
                              hipStream_t stream) {
    const float* f0   = (const float*)d_in[0];
    const float* f1   = (const float*)d_in[1];
    const float* f2   = (const float*)d_in[2];
    const float* f3   = (const float*)d_in[3];
    const float* rois = (const float*)d_in[4];
    // d_in[5] = rois_counts (unused)
    const int* level = (const int*)d_in[6];
    float* out = (float*)d_out;

    int K    = out_size / (NUM_CH * 49);     // rois
    int GBLK = (K * WPR + 3) / 4;            // level-0 global-path blocks
    int SBLK = K * 4;                        // staged blocks (roi x quarter)
    int blocks = GBLK + SBLK;
    roi_align_kernel<<<blocks, 256, LDS_BYTES, stream>>>(
        f0, f1, f2, f3, rois, level, out, K, GBLK);
}

// Round 6
// 192.319 us; speedup vs baseline: 1.2332x; 1.2332x over previous
//
#include <hip/hip_runtime.h>

// ROI Align (FPN, PH=PW=7, SR=2), fp32 I/O.
// R15: layout change. Levels 1-3 are transposed to channel-last t[b][y][x][C]
// in d_ws (26.9MB), then gathered with fully-coalesced 1KB dwordx4 loads
// (lanes over channels). Level 0 stays on the proven R11 divergent path
// (transposing l0's 82MB would cost ~26us of BW; its gather is ~17us).
// Post-mortem R14: LDS staging in channel-plane layout saves almost no
// line-touches (75 staged lines vs ~100 gather line-events per channel) and
// added runtime divisions + barriers + 14% occupancy -> 130us. Model stands:
// cost ~= line-touches per vmem instr x ~2.7cy. Channel-last makes every
// line-touch useful.
// K1 = transpose(l1,l2,l3) [BW-bound] + R11 l0-gather [TA-bound], overlapped.
// K2 = per-roi coalesced gather + LDS transpose + coalesced 50KB store.
// Fallback: ws_size < 26.9MB -> K1 handles all levels (exact R11), no K2.
// Predicted: K1 18-26us, K2 5-9us, total 28-38us (vs 73.8).

#define NUM_CH 256
#define CGRP   64
#define OFF2   5120000      // floats: 2*100*100*256
#define OFF3   6400000      // floats: OFF2 + 2*50*50*256
#define WS_FLOATS 6720000   // OFF3 + 2*25*25*256
#define TBLK_FULL 1400      // 800 (l1) + 400 (l2) + 200 (l3)

typedef float floatx2 __attribute__((ext_vector_type(2)));
typedef float floatx4 __attribute__((ext_vector_type(4)));

__device__ __forceinline__ float ext4(floatx4 v, int i) {
    float r = (i == 1) ? v.y : v.x;
    r = (i == 2) ? v.z : r;
    r = (i == 3) ? v.w : r;
    return r;
}

// ---- transpose one (b, y, ctile-of-64) row: (C,H,W) -> (H,W,C) ------------
template<int H, int W, int P>
__device__ __forceinline__ void transpose_row(
    const float* __restrict__ src, float* __restrict__ dst, int m, float* lds)
{
    int b  = m / (H * 4);
    int rm = m - b * (H * 4);
    int y  = rm >> 2;
    int ct = rm & 3;
    int tid = threadIdx.x;
    const float* s = src + (((size_t)b * NUM_CH + ct * 64) * H + y) * W;
    for (int i = tid; i < 64 * W; i += 256) {       // coalesced in x
        int c = i / W;                              // constexpr W -> magic mul
        int x = i - c * W;
        lds[c * P + x] = s[(size_t)c * (H * W) + x];
    }
    __syncthreads();
    float* d = dst + (((size_t)b * H + y) * (size_t)W) * NUM_CH + ct * 64;
    for (int i = tid; i < W * 64; i += 256) {       // coalesced in c
        int x = i >> 6;
        int c = i & 63;
        d[(size_t)x * NUM_CH + c] = lds[c * P + x]; // P odd -> conflict-free
    }
}

// ==== K1: transpose l1-3 + divergent gather (l0 only, or all on fallback) ==
__global__ __launch_bounds__(256) void k1_transpose_gather(
    const float* __restrict__ f0,
    const float* __restrict__ f1,
    const float* __restrict__ f2,
    const float* __restrict__ f3,
    const float* __restrict__ rois_f,
    const int* __restrict__ level,
    float* __restrict__ out,
    float* __restrict__ ws,
    int K, int TBLK, int all_levels)
{
    __shared__ float lds[64 * 101];                 // 25.3KB (max W=100)
    int bid = blockIdx.x;
    if (bid < TBLK) {
        if (bid < 800)       transpose_row<100, 100, 101>(f1, ws,        bid,        lds);
        else if (bid < 1200) transpose_row<50,  50,  51 >(f2, ws + OFF2, bid - 800,  lds);
        else                 transpose_row<25,  25,  27 >(f3, ws + OFF3, bid - 1200, lds);
        return;
    }

    // ---- R11 divergent-gather body (proven), gated to level 0 -------------
    int nb  = gridDim.x - TBLK;                     // = K*16, %8 == 0
    int lb  = bid - TBLK;
    int q   = nb >> 3, r = nb & 7;
    int xcd = lb & 7;
    int idx = lb >> 3;
    int l   = xcd * q + min(xcd, r) + idx;          // chunked XCD swizzle

    int NW  = K * CGRP;
    int wid = l * 4 + (int)(threadIdx.x >> 6);
    if (wid >= NW) return;
    int lane = threadIdx.x & 63;
    if (lane >= 49) return;

    int k  = wid % K;                               // roi   (inner)
    int c2 = wid / K;                               // cgrp  (outer)
    k  = __builtin_amdgcn_readfirstlane(k);
    c2 = __builtin_amdgcn_readfirstlane(c2);

    int lvl = level[k];
    if (!all_levels && lvl != 0) return;            // K2 owns levels 1-3

    const float* f;
    int H, W; float scale;
    if (lvl == 0)      { f = f0; H = 200; W = 200; scale = 0.25f;    }
    else if (lvl == 1) { f = f1; H = 100; W = 100; scale = 0.125f;   }
    else if (lvl == 2) { f = f2; H = 50;  W = 50;  scale = 0.0625f;  }
    else               { f = f3; H = 25;  W = 25;  scale = 0.03125f; }

    int p  = lane;
    int ph = p / 7;
    int pw = p % 7;

    const float* rf = rois_f + (size_t)k * 5;
    float r0 = rf[0];
    float x1 = rf[1] * scale, y1 = rf[2] * scale;
    float x2 = rf[3] * scale, y2 = rf[4] * scale;
    int bi = (int)r0;
    bi = (bi < 0) ? 0 : ((bi > 1) ? 1 : bi);

    float bh = fmaxf(y2 - y1, 1.0f) * (1.0f / 7.0f);
    float bw = fmaxf(x2 - x1, 1.0f) * (1.0f / 7.0f);

    const size_t plane = (size_t)(H * W);
    const float* base  = f + ((size_t)bi * NUM_CH + c2) * plane;
    const size_t cstr  = (size_t)CGRP * plane;

    int   rA[2], rB[2];
    float lyv[2], hyv[2], vy[2];
    #pragma unroll
    for (int sy = 0; sy < 2; ++sy) {
        float y = y1 + (float)ph * bh + ((float)sy + 0.5f) * (bh * 0.5f);
        bool valid = (y > -1.0f) && (y < (float)H);
        float yc = fmaxf(y, 0.0f);
        int yl = min((int)yc, H - 1);
        int yh = min(yl + 1, H - 1);
        float ly = (yl >= H - 1) ? 0.0f : (yc - (float)yl);
        rA[sy] = yl * W;
        rB[sy] = yh * W;
        lyv[sy] = ly; hyv[sy] = 1.0f - ly;
        vy[sy] = valid ? 0.25f : 0.0f;
    }
    int   xlv[2], xhv[2];
    float lxv[2], hxv[2], vx[2];
    #pragma unroll
    for (int sx = 0; sx < 2; ++sx) {
        float x = x1 + (float)pw * bw + ((float)sx + 0.5f) * (bw * 0.5f);
        bool valid = (x > -1.0f) && (x < (float)W);
        float xc = fmaxf(x, 0.0f);
        int xl = min((int)xc, W - 1);
        float lx = (xl >= W - 1) ? 0.0f : (xc - (float)xl);
        xlv[sx] = xl;
        xhv[sx] = min(xl + 1, W - 1);
        lxv[sx] = lx; hxv[sx] = 1.0f - lx;
        vx[sx] = valid ? 1.0f : 0.0f;
    }

    float acc[4];
    #pragma unroll
    for (int j = 0; j < 4; ++j) acc[j] = 0.0f;

    if (bw <= 3.98f) {
        int xq = min(xlv[0], W - 4);
        int i0l = min(max(xlv[0] - xq, 0), 3);
        int i0h = min(max(xhv[0] - xq, 0), 3);
        int i1l = min(max(xlv[1] - xq, 0), 3);
        int i1h = min(max(xhv[1] - xq, 0), 3);

        #pragma unroll
        for (int sy = 0; sy < 2; ++sy) {
            floatx4 LA[4], LB[4];
            #pragma unroll
            for (int j = 0; j < 4; ++j) {
                const float* bj = base + (size_t)j * cstr;
                LA[j] = *(const floatx4*)(bj + rA[sy] + xq);
                LB[j] = *(const floatx4*)(bj + rB[sy] + xq);
            }
            #pragma unroll
            for (int sx = 0; sx < 2; ++sx) {
                int il = sx ? i1l : i0l;
                int ih = sx ? i1h : i0h;
                float vs  = vy[sy] * vx[sx];
                float w00 = hyv[sy] * hxv[sx] * vs;
                float w01 = hyv[sy] * lxv[sx] * vs;
                float w10 = lyv[sy] * hxv[sx] * vs;
                float w11 = lyv[sy] * lxv[sx] * vs;
                #pragma unroll
                for (int j = 0; j < 4; ++j) {
                    acc[j] += w00 * ext4(LA[j], il) + w01 * ext4(LA[j], ih)
                            + w10 * ext4(LB[j], il) + w11 * ext4(LB[j], ih);
                }
            }
        }
    } else {
        int   xb[2];
        float sel[2];
        #pragma unroll
        for (int sx = 0; sx < 2; ++sx) {
            int xq = min(xlv[sx], W - 2);
            xb[sx]  = xq;
            sel[sx] = (xlv[sx] > xq) ? 1.0f : 0.0f;
        }
        #pragma unroll
        for (int sy = 0; sy < 2; ++sy) {
            floatx2 va[4][2], vb[4][2];
            #pragma unroll
            for (int sx = 0; sx < 2; ++sx) {
                #pragma unroll
                for (int j = 0; j < 4; ++j) {
                    const float* bj = base + (size_t)j * cstr;
                    va[j][sx] = *(const floatx2*)(bj + rA[sy] + xb[sx]);
                    vb[j][sx] = *(const floatx2*)(bj + rB[sy] + xb[sx]);
                }
            }
            #pragma unroll
            for (int sx = 0; sx < 2; ++sx) {
                float vs  = vy[sy] * vx[sx];
                float w00 = hyv[sy] * hxv[sx] * vs;
                float w01 = hyv[sy] * lxv[sx] * vs;
                float w10 = lyv[sy] * hxv[sx] * vs;
                float w11 = lyv[sy] * lxv[sx] * vs;
                float s0  = sel[sx];
                #pragma unroll
                for (int j = 0; j < 4; ++j) {
                    float v00 = va[j][sx].x + s0 * (va[j][sx].y - va[j][sx].x);
                    float v10 = vb[j][sx].x + s0 * (vb[j][sx].y - vb[j][sx].x);
                    acc[j] += w00 * v00 + w01 * va[j][sx].y
                            + w10 * v10 + w11 * vb[j][sx].y;
                }
            }
        }
    }

    size_t ob = ((size_t)k * NUM_CH + c2) * 49 + p;
    #pragma unroll
    for (int j = 0; j < 4; ++j)
        out[ob + (size_t)j * (CGRP * 49)] = acc[j];
}

// ==== K2: coalesced channel-last gather for levels 1-3 =====================
__global__ __launch_bounds__(256) void k2_gather_l123(
    const float* __restrict__ rois_f,
    const int* __restrict__ level,
    const float* __restrict__ ws,
    float* __restrict__ out,
    int K)
{
    __shared__ float lds[49 * 257];                 // 50.4KB, pitch 257 (odd)
    int k = blockIdx.x;
    int lvl = level[k];
    if (lvl == 0) return;                           // K1 owns level 0

    const float* t; int H, W; float scale;
    if (lvl == 1)      { t = ws;        H = 100; W = 100; scale = 0.125f;   }
    else if (lvl == 2) { t = ws + OFF2; H = 50;  W = 50;  scale = 0.0625f;  }
    else               { t = ws + OFF3; H = 25;  W = 25;  scale = 0.03125f; }

    const float* rf = rois_f + (size_t)k * 5;
    float r0 = rf[0];
    float x1 = rf[1] * scale, y1 = rf[2] * scale;
    float x2 = rf[3] * scale, y2 = rf[4] * scale;
    int bi = (int)r0;
    bi = (bi < 0) ? 0 : ((bi > 1) ? 1 : bi);

    float bh = fmaxf(y2 - y1, 1.0f) * (1.0f / 7.0f);
    float bw = fmaxf(x2 - x1, 1.0f) * (1.0f / 7.0f);

    const float* tb = t + (size_t)bi * H * W * NUM_CH;
    int wave = threadIdx.x >> 6;
    int lane = threadIdx.x & 63;
    int cb   = lane * 4;                            // this lane's 4 channels

    for (int px = wave; px < 49; px += 4) {
        int ph = px / 7, pw = px % 7;

        // wave-uniform geometry (identical math to the R11 path)
        int rows[4]; float lyv[2], hyv[2], vy[2];
        #pragma unroll
        for (int sy = 0; sy < 2; ++sy) {
            float y = y1 + (float)ph * bh + ((float)sy + 0.5f) * (bh * 0.5f);
            bool valid = (y > -1.0f) && (y < (float)H);
            float yc = fmaxf(y, 0.0f);
            int yl = min((int)yc, H - 1);
            int yh = min(yl + 1, H - 1);
            float ly = (yl >= H - 1) ? 0.0f : (yc - (float)yl);
            rows[2 * sy]     = yl;
            rows[2 * sy + 1] = yh;
            lyv[sy] = ly; hyv[sy] = 1.0f - ly;
            vy[sy] = valid ? 0.25f : 0.0f;
        }
        int cols[4]; float lxv[2], hxv[2], vx[2];
        #pragma unroll
        for (int sx = 0; sx < 2; ++sx) {
            float x = x1 + (float)pw * bw + ((float)sx + 0.5f) * (bw * 0.5f);
            bool valid = (x > -1.0f) && (x < (float)W);
            float xc = fmaxf(x, 0.0f);
            int xl = min((int)xc, W - 1);
            float lx = (xl >= W - 1) ? 0.0f : (xc - (float)xl);
            cols[2 * sx]     = xl;
            cols[2 * sx + 1] = min(xl + 1, W - 1);
            lxv[sx] = lx; hxv[sx] = 1.0f - lx;
            vx[sx] = valid ? 1.0f : 0.0f;
        }

        // 16 fully-coalesced 1KB loads (4 rows x 4 cols), static indexing
        floatx4 v[4][4];
        #pragma unroll
        for (int rr = 0; rr < 4; ++rr) {
            #pragma unroll
            for (int cc = 0; cc < 4; ++cc) {
                v[rr][cc] = *(const floatx4*)(
                    tb + ((size_t)rows[rr] * W + cols[cc]) * NUM_CH + cb);
            }
        }

        floatx4 acc = {0.0f, 0.0f, 0.0f, 0.0f};
        #pragma unroll
        for (int sy = 0; sy < 2; ++sy) {
            #pragma unroll
            for (int sx = 0; sx < 2; ++sx) {
                float vs  = vy[sy] * vx[sx];
                float w00 = hyv[sy] * hxv[sx] * vs;
                float w01 = hyv[sy] * lxv[sx] * vs;
                float w10 = lyv[sy] * hxv[sx] * vs;
                float w11 = lyv[sy] * lxv[sx] * vs;
                acc += v[2 * sy][2 * sx]     * w00;
                acc += v[2 * sy][2 * sx + 1] * w01;
                acc += v[2 * sy + 1][2 * sx]     * w10;
                acc += v[2 * sy + 1][2 * sx + 1] * w11;
            }
        }

        int lb = px * 257 + cb;                     // 8-way on write, ok
        lds[lb + 0] = acc.x;
        lds[lb + 1] = acc.y;
        lds[lb + 2] = acc.z;
        lds[lb + 3] = acc.w;
    }
    __syncthreads();

    // coalesced 50KB store; LDS read stride 257 (odd) -> conflict-free
    float* ob = out + (size_t)k * (NUM_CH * 49);
    for (int i = threadIdx.x; i < NUM_CH * 49; i += 256) {
        int c  = i / 49;                            // const divisor -> magic
        int px = i - c * 49;
        ob[i] = lds[px * 257 + c];
    }
}

extern "C" void kernel_launch(void* const* d_in, const int* in_sizes, int n_in,
                              void* d_out, int out_size, void* d_ws, size_t ws_size,
                              hipStream_t stream) {
    const float* f0   = (const float*)d_in[0];
    const float* f1   = (const float*)d_in[1];
    const float* f2   = (const float*)d_in[2];
    const float* f3   = (const float*)d_in[3];
    const float* rois = (const float*)d_in[4];
    // d_in[5] = rois_counts (unused)
    const int* level = (const int*)d_in[6];
    float* out = (float*)d_out;

    int K = out_size / (NUM_CH * 49);
    int use_ws = (ws_size >= (size_t)WS_FLOATS * 4) ? 1 : 0;
    int TBLK = use_ws ? TBLK_FULL : 0;
    int GB   = K * 16;                   // R11 gather region: K*64 waves

    k1_transpose_gather<<<TBLK + GB, 256, 0, stream>>>(
        f0, f1, f2, f3, rois, level, out, (float*)d_ws, K, TBLK, use_ws ? 0 : 1);
    if (use_ws) {
        k2_gather_l123<<<K, 256, 0, stream>>>(
            rois, level, (const float*)d_ws, out, K);
    }
}